// Round 9
// baseline (189.400 us; speedup 1.0000x reference)
//
#include <hip/hip_runtime.h>

// CP-decomposed 3D conv (AirConv3D): B=1, Cin=32, Cout=64, 56^3, K=3, pad=1, rank=53.
// All-f32 (R1-R5). ws ~268 MB. R9: occupancy repair — k1/k3 get 4x wave counts.
//   k0_t : transpose Ucin -> Ut[r][c] in ws after T1
//   k1r  : pointwise 32->53, grid (686,4): z splits ranks. s_load weights, no LDS.
//   k2n  : per-(r,h)-plane d-conv + w-conv in place on T1 (float4 global+LDS).
//   k3s  : fused h-conv + projection + bias, grid (686,4): y splits o-space,
//          wave owns 4 out-channels (og uniform -> s_load weights).
// Fallback (small ws): R5 pipeline (known good).

#define NP 175616   // 56*56*56
#define NQ 43904    // NP/4 float4 columns
#define HSTR 3136   // 56*56
#define QH 784      // HSTR/4 quads per h-plane
#define CIN 32
#define RK 53
#define COUT 64
#define SCR 53      // fallback scratch slice base in d_out

// ---- k0: Ut[r*32+c] = Ucin[c*53+r] ----
__global__ __launch_bounds__(256) void k0_t(const float* __restrict__ Ucin,
                                            float* __restrict__ Ut)
{
    int t = blockIdx.x * 256 + threadIdx.x;
    if (t < RK * CIN) {
        int r = t >> 5, c = t & 31;
        Ut[t] = Ucin[c * RK + r];
    }
}

// ---- k1r: T1[r,p] = sum_c x[c,p] * Ut[r][c], ranks split over blockIdx.y ----
__global__ __launch_bounds__(256) void k1r(
    const float* __restrict__ x, const float* __restrict__ Ut,
    float* __restrict__ T1)
{
    const int p = blockIdx.x * 256 + threadIdx.x;
    const int z = blockIdx.y;
    const int r0 = (z * RK) >> 2;          // 0,13,26,39
    const int r1 = ((z + 1) * RK) >> 2;    // 13,26,39,53
    float xv[CIN];
#pragma unroll
    for (int c = 0; c < CIN; ++c) xv[c] = x[c * NP + p];
#pragma unroll 2
    for (int r = r0; r < r1; ++r) {
        const float* U = Ut + r * CIN;      // uniform -> s_load
        float acc = 0.f;
#pragma unroll
        for (int c = 0; c < CIN; ++c) acc += xv[c] * U[c];
        T1[(size_t)r * NP + p] = acc;
    }
}

// ---- k2n: in-plane d-conv + w-conv, in place on T1. grid (56 h, 53 r) ----
__global__ __launch_bounds__(256) void k2n(
    float* T1, const float* __restrict__ Ukw, const float* __restrict__ Ukd)
{
    __shared__ float sIn[3136];
    __shared__ float sA[3136];
    const int h = blockIdx.x;
    const int r = blockIdx.y;
    const int tid = threadIdx.x;
    const float kd0 = Ukd[r], kd1 = Ukd[RK + r], kd2 = Ukd[2 * RK + r];
    const float kw0 = Ukw[r], kw1 = Ukw[RK + r], kw2 = Ukw[2 * RK + r];
    float4* P4 = (float4*)(T1 + (size_t)r * NP + h * HSTR);

    for (int i = tid; i < QH; i += 256)
        ((float4*)sIn)[i] = P4[i];
    __syncthreads();

    for (int i = tid; i < QH; i += 256) {        // d-conv
        int w = i / 14, d0 = (i - w * 14) * 4;
        const float* b = &sIn[w * 56 + d0];
        float4 c = *(const float4*)b;
        float lm = (d0 > 0)  ? b[-1] : 0.f;
        float rp = (d0 < 52) ? b[4]  : 0.f;
        float4 o;
        o.x = lm  * kd0 + c.x * kd1 + c.y * kd2;
        o.y = c.x * kd0 + c.y * kd1 + c.z * kd2;
        o.z = c.y * kd0 + c.z * kd1 + c.w * kd2;
        o.w = c.z * kd0 + c.w * kd1 + rp  * kd2;
        ((float4*)sA)[i] = o;
    }
    __syncthreads();

    for (int i = tid; i < QH; i += 256) {        // w-conv, write back in place
        int w = i / 14;
        float4 m = ((const float4*)sA)[i];
        float4 a0, a2;
        a0.x = a0.y = a0.z = a0.w = 0.f; a2 = a0;
        if (w > 0)  a0 = ((const float4*)sA)[i - 14];
        if (w < 55) a2 = ((const float4*)sA)[i + 14];
        float4 res;
        res.x = a0.x * kw0 + m.x * kw1 + a2.x * kw2;
        res.y = a0.y * kw0 + m.y * kw1 + a2.y * kw2;
        res.z = a0.z * kw0 + m.z * kw1 + a2.z * kw2;
        res.w = a0.w * kw0 + m.w * kw1 + a2.w * kw2;
        P4[i] = res;
    }
}

// ---- k3s: out[o,q] = sum_r kh-blend(Ta[r,h-1..h+1,q]) * Ucout[r][o] + bias[o] ----
// grid (686, 4); wave owns og = (y*4 + waveId)*4 -> 4 out-channels per thread.
__global__ __launch_bounds__(256, 4) void k3s(
    const float4* __restrict__ Ta, const float* __restrict__ Ucout,
    const float* __restrict__ bias, const float* __restrict__ Ukh,
    float4* __restrict__ Out)
{
    const int lane = threadIdx.x & 63;
    int og = ((blockIdx.y << 2) | (threadIdx.x >> 6)) << 2;   // 0..60 step 4
    og = __builtin_amdgcn_readfirstlane(og);
    const int q = blockIdx.x * 64 + lane;
    const int h = q / QH;
    const bool hm = (h > 0), hp = (h < 55);

    float4 a[4];
#pragma unroll
    for (int o = 0; o < 4; ++o) {
        float b = bias[og + o];
        a[o].x = b; a[o].y = b; a[o].z = b; a[o].w = b;
    }
#pragma unroll 2
    for (int r = 0; r < RK; ++r) {
        const float4* S = Ta + (size_t)r * NQ + q;
        const float k0 = Ukh[r], k1 = Ukh[RK + r], k2 = Ukh[2 * RK + r];
        float4 B = S[0];
        float4 A; A.x = 0.f; A.y = 0.f; A.z = 0.f; A.w = 0.f;
        float4 C = A;
        if (hm) A = S[-QH];
        if (hp) C = S[QH];
        float4 t;
        t.x = A.x * k0 + B.x * k1 + C.x * k2;
        t.y = A.y * k0 + B.y * k1 + C.y * k2;
        t.z = A.z * k0 + B.z * k1 + C.z * k2;
        t.w = A.w * k0 + B.w * k1 + C.w * k2;
        const float* Ur = Ucout + r * COUT + og;   // uniform -> s_load_dwordx4
#pragma unroll
        for (int o = 0; o < 4; ++o) {
            float u = Ur[o];
            a[o].x += t.x * u; a[o].y += t.y * u;
            a[o].z += t.z * u; a[o].w += t.w * u;
        }
    }
#pragma unroll
    for (int o = 0; o < 4; ++o)
        Out[(size_t)(og + o) * NQ + q] = a[o];
}

// ===================== fallback path (R5, known good) =====================

__global__ __launch_bounds__(256) void k1_chunk(
    const float* __restrict__ x, const float* __restrict__ Ucin,
    float* T, int r0, int nr)
{
    __shared__ float sU[11 * CIN];
    const int tid = threadIdx.x;
    for (int t = tid; t < nr * CIN; t += 256) {
        int lr = t >> 5, c = t & 31;
        sU[t] = Ucin[c * RK + (r0 + lr)];
    }
    __syncthreads();
    const int p = blockIdx.x * 256 + tid;
    float xv[CIN];
#pragma unroll
    for (int c = 0; c < CIN; ++c) xv[c] = x[c * NP + p];
#pragma unroll 1
    for (int lr = 0; lr < nr; ++lr) {
        float acc = 0.f;
#pragma unroll
        for (int c = 0; c < CIN; ++c) acc += xv[c] * sU[lr * CIN + c];
        T[(size_t)(SCR + lr) * NP + p] = acc;
    }
}

__global__ __launch_bounds__(256) void k2_chunk(
    const float* __restrict__ Ukh, const float* __restrict__ Ukw,
    const float* __restrict__ Ukd, float* T, int r0)
{
    __shared__ float sIn[5800];
    __shared__ float sA[5600];
    const int lr = blockIdx.z;
    const int r  = r0 + lr;
    const int h0 = blockIdx.x * 8, w0 = blockIdx.y * 8;
    const int tid = threadIdx.x;
    const float kh0 = Ukh[r], kh1 = Ukh[RK + r], kh2 = Ukh[2 * RK + r];
    const float kw0 = Ukw[r], kw1 = Ukw[RK + r], kw2 = Ukw[2 * RK + r];
    const float kd0 = Ukd[r], kd1 = Ukd[RK + r], kd2 = Ukd[2 * RK + r];
    const float* T1r = T + (size_t)(SCR + lr) * NP;

    for (int idx = tid; idx < 5800; idx += 256) {
        int d = idx % 58; int t2 = idx / 58; int ww = t2 % 10; int hh = t2 / 10;
        int gh = h0 + hh - 1, gw = w0 + ww - 1, gd = d - 1;
        float v = 0.f;
        if ((unsigned)gh < 56u && (unsigned)gw < 56u && (unsigned)gd < 56u)
            v = T1r[gh * HSTR + gw * 56 + gd];
        sIn[idx] = v;
    }
    __syncthreads();
    for (int idx = tid; idx < 5600; idx += 256) {
        int d = idx % 56; int t2 = idx / 56; int ww = t2 % 10; int hh = t2 / 10;
        const float* b = &sIn[(hh * 10 + ww) * 58 + d];
        sA[idx] = b[0] * kd0 + b[1] * kd1 + b[2] * kd2;
    }
    __syncthreads();
    const float k00 = kh0 * kw0, k01 = kh0 * kw1, k02 = kh0 * kw2;
    const float k10 = kh1 * kw0, k11 = kh1 * kw1, k12 = kh1 * kw2;
    const float k20 = kh2 * kw0, k21 = kh2 * kw1, k22 = kh2 * kw2;
    for (int idx = tid; idx < 3584; idx += 256) {
        int d = idx % 56; int t2 = idx / 56; int ww = t2 % 8; int hh = t2 / 8;
        const float* a = &sA[(hh * 10 + ww) * 56 + d];
        float acc = a[0]    * k00 + a[56]   * k01 + a[112]  * k02
                  + a[560]  * k10 + a[616]  * k11 + a[672]  * k12
                  + a[1120] * k20 + a[1176] * k21 + a[1232] * k22;
        T[(size_t)r * NP + (h0 + hh) * HSTR + (w0 + ww) * 56 + d] = acc;
    }
}

__global__ __launch_bounds__(256) void k3_out(
    float* T, const float* __restrict__ Ucout, const float* __restrict__ bias)
{
    __shared__ float sUo[RK * COUT];
    __shared__ float sB[COUT];
    const int tid = threadIdx.x;
    for (int t = tid; t < RK * COUT; t += 256) sUo[t] = Ucout[t];
    if (tid < COUT) sB[tid] = bias[tid];
    __syncthreads();
    const int p = blockIdx.x * 256 + tid;
    float acc[COUT];
#pragma unroll
    for (int o = 0; o < COUT; ++o) acc[o] = sB[o];
#pragma unroll 1
    for (int r = 0; r < RK; ++r) {
        float t = T[(size_t)r * NP + p];
        const float* Ur = &sUo[r * COUT];
#pragma unroll
        for (int o = 0; o < COUT; ++o) acc[o] += t * Ur[o];
    }
#pragma unroll
    for (int o = 0; o < COUT; ++o) T[(size_t)o * NP + p] = acc[o];
}

// ===================== launch =====================

extern "C" void kernel_launch(void* const* d_in, const int* in_sizes, int n_in,
                              void* d_out, int out_size, void* d_ws, size_t ws_size,
                              hipStream_t stream)
{
    const float* x     = (const float*)d_in[0];
    const float* Ukh   = (const float*)d_in[1];
    const float* Ukw   = (const float*)d_in[2];
    const float* Ukd   = (const float*)d_in[3];
    const float* Ucin  = (const float*)d_in[4];
    const float* Ucout = (const float*)d_in[5];
    const float* bias  = (const float*)d_in[6];

    const size_t t1_bytes = (size_t)RK * NP * sizeof(float);   // 37.2 MB

    if (ws_size >= t1_bytes + 8192) {
        float* T1 = (float*)d_ws;
        float* Ut = (float*)((char*)d_ws + t1_bytes);          // 6.8 KB
        k0_t<<<7, 256, 0, stream>>>(Ucin, Ut);
        k1r<<<dim3(NP / 256, 4), 256, 0, stream>>>(x, Ut, T1);
        k2n<<<dim3(56, RK), 256, 0, stream>>>(T1, Ukw, Ukd);
        k3s<<<dim3(NQ / 64, 4), 256, 0, stream>>>((const float4*)T1, Ucout, bias,
                                                  Ukh, (float4*)d_out);
    } else {
        float* T = (float*)d_out;
        for (int r0 = 0; r0 < RK; r0 += 11) {
            int nr = (RK - r0 < 11) ? (RK - r0) : 11;
            k1_chunk<<<NP / 256, 256, 0, stream>>>(x, Ucin, T, r0, nr);
            k2_chunk<<<dim3(7, 7, nr), 256, 0, stream>>>(Ukh, Ukw, Ukd, T, r0);
        }
        k3_out<<<NP / 256, 256, 0, stream>>>(T, Ucout, bias);
    }
}

// Round 10
// 159.204 us; speedup vs baseline: 1.1897x; 1.1897x over previous
//
#include <hip/hip_runtime.h>

// CP-decomposed 3D conv (AirConv3D): B=1, Cin=32, Cout=64, 56^3, K=3, pad=1, rank=53.
// All-f32 (R1-R5). ws ~268 MB. R9 lesson: block-splitting a reduction reader
// multiplies HBM traffic (no cross-XCD L2 reuse) — k1/k3 stay single-pass.
// R10:
//   k0_t : Ucin^T -> Ut[r][c] in ws after T1
//   k1d  : pointwise 32->53 FUSED with d-conv via in-wave __shfl (row of 56 d
//          = lanes 0..55 of one wave). No LDS, no extra traffic. T1d -> ws.
//   k2w  : w-conv only, in place on T1d (one LDS stage, one barrier).
//   k3f2 : h-conv + 53->64 projection + bias, float2 lanes -> 1372 blocks
//          (2x waves of R8) with single-pass T1 traffic. og uniform -> s_load.
// Fallback (small ws): R5 pipeline (known good).

#define NP 175616   // 56*56*56
#define NP2 87808   // NP/2 float2 columns
#define HSTR 3136   // 56*56
#define H2 1568     // HSTR/2 float2 per h-plane
#define QH 784      // HSTR/4 quads per h-plane
#define CIN 32
#define RK 53
#define COUT 64
#define SCR 53      // fallback scratch slice base in d_out

// ---- k0: Ut[r*32+c] = Ucin[c*53+r] ----
__global__ __launch_bounds__(256) void k0_t(const float* __restrict__ Ucin,
                                            float* __restrict__ Ut)
{
    int t = blockIdx.x * 256 + threadIdx.x;
    if (t < RK * CIN) {
        int r = t >> 5, c = t & 31;
        Ut[t] = Ucin[c * RK + r];
    }
}

// ---- k1d: T1d[r,p] = d-conv(sum_c x[c,p]*Ut[r][c]) via wave shfl ----
// Block = 256 threads = 4 waves; wave = one d-row (lanes 0..55 active).
__global__ __launch_bounds__(256) void k1d(
    const float* __restrict__ x, const float* __restrict__ Ut,
    const float* __restrict__ Ukd, float* __restrict__ T1d)
{
    const int lane = threadIdx.x & 63;          // d index
    const int row  = blockIdx.x * 4 + (threadIdx.x >> 6);   // (h,w) row in [0,3136)
    const int p    = row * 56 + lane;
    const bool act = (lane < 56);

    float xv[CIN];
#pragma unroll
    for (int c = 0; c < CIN; ++c) xv[c] = act ? x[c * NP + p] : 0.f;

#pragma unroll 2
    for (int r = 0; r < RK; ++r) {
        const float* U = Ut + r * CIN;          // uniform -> s_load
        float acc = 0.f;
#pragma unroll
        for (int c = 0; c < CIN; ++c) acc += xv[c] * U[c];
        // d-conv: out[d] = in[d-1]*kd0 + in[d]*kd1 + in[d+1]*kd2, zero pad
        float lm = __shfl_up(acc, 1, 64);
        float rp = __shfl_down(acc, 1, 64);
        if (lane == 0)  lm = 0.f;
        if (lane == 55) rp = 0.f;
        float res = lm * Ukd[r] + acc * Ukd[RK + r] + rp * Ukd[2 * RK + r];
        if (act) T1d[(size_t)r * NP + p] = res;
    }
}

// ---- k2w: w-conv in place on T1d. grid (56 h, 53 r) ----
__global__ __launch_bounds__(256) void k2w(
    float* T1d, const float* __restrict__ Ukw)
{
    __shared__ float sIn[3136];                  // one h-plane, 12.5 KB
    const int h = blockIdx.x;
    const int r = blockIdx.y;
    const int tid = threadIdx.x;
    const float kw0 = Ukw[r], kw1 = Ukw[RK + r], kw2 = Ukw[2 * RK + r];
    float4* P4 = (float4*)(T1d + (size_t)r * NP + h * HSTR);

    for (int i = tid; i < QH; i += 256)
        ((float4*)sIn)[i] = P4[i];
    __syncthreads();

    for (int i = tid; i < QH; i += 256) {
        int w = i / 14;
        float4 m = ((const float4*)sIn)[i];
        float4 a0, a2;
        a0.x = a0.y = a0.z = a0.w = 0.f; a2 = a0;
        if (w > 0)  a0 = ((const float4*)sIn)[i - 14];
        if (w < 55) a2 = ((const float4*)sIn)[i + 14];
        float4 res;
        res.x = a0.x * kw0 + m.x * kw1 + a2.x * kw2;
        res.y = a0.y * kw0 + m.y * kw1 + a2.y * kw2;
        res.z = a0.z * kw0 + m.z * kw1 + a2.z * kw2;
        res.w = a0.w * kw0 + m.w * kw1 + a2.w * kw2;
        P4[i] = res;
    }
}

// ---- k3f2: out[o,q2] = sum_r kh-blend(Ta[r,h-1..h+1,q2]) * Ucout[r][o] + bias ----
// float2 lanes: 1372 blocks x 4 waves; wave owns 16 out-channels (og uniform).
__global__ __launch_bounds__(256, 4) void k3f2(
    const float2* __restrict__ Ta, const float* __restrict__ Ucout,
    const float* __restrict__ bias, const float* __restrict__ Ukh,
    float2* __restrict__ Out)
{
    const int lane = threadIdx.x & 63;
    int og = (threadIdx.x >> 6) << 4;            // 0,16,32,48
    og = __builtin_amdgcn_readfirstlane(og);
    const int q = blockIdx.x * 64 + lane;        // float2 column
    const int h = q / H2;
    const bool hm = (h > 0), hp = (h < 55);

    float2 a[16];
#pragma unroll
    for (int o = 0; o < 16; ++o) {
        float b = bias[og + o];
        a[o].x = b; a[o].y = b;
    }
#pragma unroll 2
    for (int r = 0; r < RK; ++r) {
        const float2* S = Ta + (size_t)r * NP2 + q;
        const float k0 = Ukh[r], k1 = Ukh[RK + r], k2 = Ukh[2 * RK + r];
        float2 B = S[0];
        float2 A; A.x = 0.f; A.y = 0.f;
        float2 C = A;
        if (hm) A = S[-H2];
        if (hp) C = S[H2];
        float2 t;
        t.x = A.x * k0 + B.x * k1 + C.x * k2;
        t.y = A.y * k0 + B.y * k1 + C.y * k2;
        const float* Ur = Ucout + r * COUT + og;   // uniform -> s_load
#pragma unroll
        for (int o = 0; o < 16; ++o) {
            float u = Ur[o];
            a[o].x += t.x * u; a[o].y += t.y * u;
        }
    }
#pragma unroll
    for (int o = 0; o < 16; ++o)
        Out[(size_t)(og + o) * NP2 + q] = a[o];
}

// ===================== fallback path (R5, known good) =====================

__global__ __launch_bounds__(256) void k1_chunk(
    const float* __restrict__ x, const float* __restrict__ Ucin,
    float* T, int r0, int nr)
{
    __shared__ float sU[11 * CIN];
    const int tid = threadIdx.x;
    for (int t = tid; t < nr * CIN; t += 256) {
        int lr = t >> 5, c = t & 31;
        sU[t] = Ucin[c * RK + (r0 + lr)];
    }
    __syncthreads();
    const int p = blockIdx.x * 256 + tid;
    float xv[CIN];
#pragma unroll
    for (int c = 0; c < CIN; ++c) xv[c] = x[c * NP + p];
#pragma unroll 1
    for (int lr = 0; lr < nr; ++lr) {
        float acc = 0.f;
#pragma unroll
        for (int c = 0; c < CIN; ++c) acc += xv[c] * sU[lr * CIN + c];
        T[(size_t)(SCR + lr) * NP + p] = acc;
    }
}

__global__ __launch_bounds__(256) void k2_chunk(
    const float* __restrict__ Ukh, const float* __restrict__ Ukw,
    const float* __restrict__ Ukd, float* T, int r0)
{
    __shared__ float sIn[5800];
    __shared__ float sA[5600];
    const int lr = blockIdx.z;
    const int r  = r0 + lr;
    const int h0 = blockIdx.x * 8, w0 = blockIdx.y * 8;
    const int tid = threadIdx.x;
    const float kh0 = Ukh[r], kh1 = Ukh[RK + r], kh2 = Ukh[2 * RK + r];
    const float kw0 = Ukw[r], kw1 = Ukw[RK + r], kw2 = Ukw[2 * RK + r];
    const float kd0 = Ukd[r], kd1 = Ukd[RK + r], kd2 = Ukd[2 * RK + r];
    const float* T1r = T + (size_t)(SCR + lr) * NP;

    for (int idx = tid; idx < 5800; idx += 256) {
        int d = idx % 58; int t2 = idx / 58; int ww = t2 % 10; int hh = t2 / 10;
        int gh = h0 + hh - 1, gw = w0 + ww - 1, gd = d - 1;
        float v = 0.f;
        if ((unsigned)gh < 56u && (unsigned)gw < 56u && (unsigned)gd < 56u)
            v = T1r[gh * HSTR + gw * 56 + gd];
        sIn[idx] = v;
    }
    __syncthreads();
    for (int idx = tid; idx < 5600; idx += 256) {
        int d = idx % 56; int t2 = idx / 56; int ww = t2 % 10; int hh = t2 / 10;
        const float* b = &sIn[(hh * 10 + ww) * 58 + d];
        sA[idx] = b[0] * kd0 + b[1] * kd1 + b[2] * kd2;
    }
    __syncthreads();
    const float k00 = kh0 * kw0, k01 = kh0 * kw1, k02 = kh0 * kw2;
    const float k10 = kh1 * kw0, k11 = kh1 * kw1, k12 = kh1 * kw2;
    const float k20 = kh2 * kw0, k21 = kh2 * kw1, k22 = kh2 * kw2;
    for (int idx = tid; idx < 3584; idx += 256) {
        int d = idx % 56; int t2 = idx / 56; int ww = t2 % 8; int hh = t2 / 8;
        const float* a = &sA[(hh * 10 + ww) * 56 + d];
        float acc = a[0]    * k00 + a[56]   * k01 + a[112]  * k02
                  + a[560]  * k10 + a[616]  * k11 + a[672]  * k12
                  + a[1120] * k20 + a[1176] * k21 + a[1232] * k22;
        T[(size_t)r * NP + (h0 + hh) * HSTR + (w0 + ww) * 56 + d] = acc;
    }
}

__global__ __launch_bounds__(256) void k3_out(
    float* T, const float* __restrict__ Ucout, const float* __restrict__ bias)
{
    __shared__ float sUo[RK * COUT];
    __shared__ float sB[COUT];
    const int tid = threadIdx.x;
    for (int t = tid; t < RK * COUT; t += 256) sUo[t] = Ucout[t];
    if (tid < COUT) sB[tid] = bias[tid];
    __syncthreads();
    const int p = blockIdx.x * 256 + tid;
    float acc[COUT];
#pragma unroll
    for (int o = 0; o < COUT; ++o) acc[o] = sB[o];
#pragma unroll 1
    for (int r = 0; r < RK; ++r) {
        float t = T[(size_t)r * NP + p];
        const float* Ur = &sUo[r * COUT];
#pragma unroll
        for (int o = 0; o < COUT; ++o) acc[o] += t * Ur[o];
    }
#pragma unroll
    for (int o = 0; o < COUT; ++o) T[(size_t)o * NP + p] = acc[o];
}

// ===================== launch =====================

extern "C" void kernel_launch(void* const* d_in, const int* in_sizes, int n_in,
                              void* d_out, int out_size, void* d_ws, size_t ws_size,
                              hipStream_t stream)
{
    const float* x     = (const float*)d_in[0];
    const float* Ukh   = (const float*)d_in[1];
    const float* Ukw   = (const float*)d_in[2];
    const float* Ukd   = (const float*)d_in[3];
    const float* Ucin  = (const float*)d_in[4];
    const float* Ucout = (const float*)d_in[5];
    const float* bias  = (const float*)d_in[6];

    const size_t t1_bytes = (size_t)RK * NP * sizeof(float);   // 37.2 MB

    if (ws_size >= t1_bytes + 8192) {
        float* T1 = (float*)d_ws;
        float* Ut = (float*)((char*)d_ws + t1_bytes);          // 6.8 KB
        k0_t<<<7, 256, 0, stream>>>(Ucin, Ut);
        k1d<<<HSTR / 4, 256, 0, stream>>>(x, Ut, Ukd, T1);     // 784 blocks
        k2w<<<dim3(56, RK), 256, 0, stream>>>(T1, Ukw);
        k3f2<<<NP2 / 64, 256, 0, stream>>>((const float2*)T1, Ucout, bias, Ukh,
                                           (float2*)d_out);
    } else {
        float* T = (float*)d_out;
        for (int r0 = 0; r0 < RK; r0 += 11) {
            int nr = (RK - r0 < 11) ? (RK - r0) : 11;
            k1_chunk<<<NP / 256, 256, 0, stream>>>(x, Ucin, T, r0, nr);
            k2_chunk<<<dim3(7, 7, nr), 256, 0, stream>>>(Ukh, Ukw, Ukd, T, r0);
        }
        k3_out<<<NP / 256, 256, 0, stream>>>(T, Ucout, bias);
    }
}